// Round 7
// baseline (908.126 us; speedup 1.0000x reference)
//
#include <hip/hip_runtime.h>

#define NN   20000   // nodes
#define NE   160000  // edges
#define HD   32      // hidden / in dim
#define EFD  95      // edge feature dim
#define EHD  64      // edge hidden dim
#define NG   64      // graphs
#define EPSF 1e-5f
#define EPW  32      // edges per wave (edge_mlp_v5)

// ---------------------------------------------------------------- zero fill
__global__ __launch_bounds__(256) void zero_kernel(float* __restrict__ p, int n) {
    int i = blockIdx.x * 256 + threadIdx.x;
    if (i < n) p[i] = 0.f;
}

// ---------------------------------------------------------------- CSR build: histogram
__global__ __launch_bounds__(256) void hist_kernel(const int* __restrict__ idx,
                                                   int* __restrict__ hist) {
    const int e = blockIdx.x * 256 + threadIdx.x;   // grid exactly NE/256
    atomicAdd(&hist[idx[e]], 1);
}

// ---------------------------------------------------------------- CSR build: exclusive scan (single block)
__global__ __launch_bounds__(1024) void scan_kernel(const int* __restrict__ hist,
                                                    int* __restrict__ rowptr,
                                                    int* __restrict__ cursor) {
    __shared__ int part[1024];
    const int t = threadIdx.x;
    const int base = t * 20;
    int s = 0;
    #pragma unroll
    for (int k = 0; k < 20; ++k) {
        const int idx = base + k;
        if (idx < NN) s += hist[idx];
    }
    part[t] = s;
    __syncthreads();
    for (int off = 1; off < 1024; off <<= 1) {
        int v = 0;
        if (t >= off) v = part[t - off];
        __syncthreads();
        if (t >= off) part[t] += v;
        __syncthreads();
    }
    int run = part[t] - s;   // exclusive offset for this chunk
    #pragma unroll
    for (int k = 0; k < 20; ++k) {
        const int idx = base + k;
        if (idx < NN) {
            rowptr[idx] = run;
            cursor[idx] = run;
            run += hist[idx];
        }
    }
    if (t == 0) rowptr[NN] = NE;
}

// ---------------------------------------------------------------- dst scatter -> sortpos_d
__global__ __launch_bounds__(256) void scatter_dst_kernel(const int* __restrict__ dst,
                                                          int* __restrict__ cursor,
                                                          int* __restrict__ sortpos) {
    const int e = blockIdx.x * 256 + threadIdx.x;
    sortpos[e] = atomicAdd(&cursor[dst[e]], 1);
}

// ---------------------------------------------------------------- src scatter -> ssorted/wpos/esorted
__global__ __launch_bounds__(256) void scatter_src_kernel(const int* __restrict__ src,
                                                          const int* __restrict__ sortpos_d,
                                                          int* __restrict__ cursor,
                                                          int* __restrict__ ssorted,
                                                          int* __restrict__ wpos,
                                                          int* __restrict__ esorted) {
    const int e = blockIdx.x * 256 + threadIdx.x;
    const int s = src[e];
    const int pos = atomicAdd(&cursor[s], 1);
    ssorted[pos] = s;            // src node of sorted slot
    wpos[pos]    = sortpos_d[e]; // where slot's msg goes (dst-sorted)
    esorted[pos] = e;            // edge id of sorted slot (for h gather)
}

// ---------------------------------------------------------------- edge MLP (fallback path, hT output)
__global__ __launch_bounds__(256) void edge_mlp_kernel(
    const float* __restrict__ ea, const float* __restrict__ W1,
    const float* __restrict__ b1, float* __restrict__ hT)   // EHD x NE
{
    __shared__ float elds[128 * EFD];
    const int tid = threadIdx.x;
    const int e0  = blockIdx.x * 128;
    const float4* s4 = reinterpret_cast<const float4*>(ea + (size_t)e0 * EFD);
    float4* d4 = reinterpret_cast<float4*>(elds);
    #pragma unroll
    for (int i = 0; i < 12; ++i) {
        const int idx = tid + i * 256;
        if (idx < (128 * EFD / 4)) d4[idx] = s4[idx];
    }
    __syncthreads();
    const int el = tid & 127;
    const int hh = (tid >> 7) * 32;
    const int e  = e0 + el;
    float acc[32];
    #pragma unroll
    for (int k = 0; k < 32; ++k) acc[k] = b1[hh + k];
    const float* er = elds + el * EFD;
    #pragma unroll 5
    for (int j = 0; j < EFD; ++j) {
        const float ej = er[j];
        const float* w1r = W1 + j * EHD + hh;
        #pragma unroll
        for (int k = 0; k < 32; ++k)
            acc[k] = fmaf(ej, w1r[k], acc[k]);
    }
    #pragma unroll
    for (int k = 0; k < 32; ++k)
        hT[(hh + k) * NE + e] = fmaxf(acc[k], 0.f);
}

// ---------------------------------------------------------------- edge MLP v5: lane-owns-output-column
// One wave per block (blockDim=64 -> e0+t is PROVABLY workgroup-uniform ->
// ea row streams via s_load through K$; consecutive edges keep lines hot).
// Lane k holds W1 column k in 95 VGPRs (loaded once, coalesced 256B/j).
// Inner loop: 95 v_fmac (SGPR operand) per edge -- no LDS, no syncthreads,
// no per-iteration W1 refetch (the round-6 stall: s_load chain serialized
// per j with only 1.6 waves/SIMD to hide it). Store: lane-consecutive 256B.
__global__ __launch_bounds__(64) void edge_mlp_v5_kernel(
    const float* __restrict__ ea,    // NE x 95
    const float* __restrict__ W1,    // 95 x 64
    const float* __restrict__ b1,    // 64
    float*       __restrict__ hs)    // NE x 64, rows by edge id
{
    const int k  = threadIdx.x;           // output column, 0..63
    const int e0 = blockIdx.x * EPW;      // grid exactly NE/EPW

    // W1 column k -> registers (95 VGPRs; coalesced across lanes)
    float w[EFD];
    #pragma unroll
    for (int j = 0; j < EFD; ++j) w[j] = W1[j * EHD + k];
    const float bk = b1[k];

    for (int t = 0; t < EPW; ++t) {
        const float* er = ea + (size_t)(e0 + t) * EFD;   // wave-uniform -> s_load
        float a = bk;
        #pragma unroll
        for (int j = 0; j < EFD; ++j)
            a = fmaf(er[j], w[j], a);
        hs[(size_t)(e0 + t) * EHD + k] = fmaxf(a, 0.f);  // 256B coalesced
    }
}

// ---------------------------------------------------------------- T = x @ W2r : T[n, kh*32+o] = sum_i x[n,i]*W2[kh][i*32+o]
__global__ __launch_bounds__(256) void tmat_kernel(
    const float* __restrict__ xin,   // NN x 32
    const float* __restrict__ W2,    // 64 x 1024
    float*       __restrict__ T)     // NN x 2048
{
    const int nb = blockIdx.x * 8;
    const int c  = blockIdx.y * 256 + threadIdx.x;   // 0..2047
    const int kh = c >> 5, o = c & 31;

    float w[32];
    const float* wp = W2 + kh * 1024 + o;
    #pragma unroll
    for (int i = 0; i < 32; ++i) w[i] = wp[i * 32];  // 128B coalesced / group

    #pragma unroll
    for (int nj = 0; nj < 8; ++nj) {
        const float* xr = xin + (nb + nj) * HD;      // uniform -> s_load
        float a0 = 0.f, a1 = 0.f;
        #pragma unroll
        for (int i = 0; i < 32; i += 2) {
            a0 = fmaf(xr[i],     w[i],     a0);
            a1 = fmaf(xr[i + 1], w[i + 1], a1);
        }
        T[(size_t)(nb + nj) * 2048 + c] = a0 + a1;   // 1KB coalesced / node
    }
}

// ---------------------------------------------------------------- bvec[n,o] = sum_i x[n,i]*b2[i*32+o]
__global__ __launch_bounds__(256) void bvec_kernel(
    const float* __restrict__ xin, const float* __restrict__ b2,
    float* __restrict__ bv)
{
    const int gid = blockIdx.x * 256 + threadIdx.x;  // NN*32/256
    const int n = gid >> 5, o = gid & 31;
    const float* xr = xin + n * HD;
    float a = 0.f;
    #pragma unroll
    for (int i = 0; i < 32; ++i)
        a = fmaf(xr[i], b2[i * HD + o], a);
    bv[gid] = a;
}

// ---------------------------------------------------------------- per-edge contraction over kh, src-sorted
// grid NE/8, block 256 = 8 slots x 32 o. h rows gathered via esorted
// (16 lanes x 256B contiguous per row). msg written at dst-sorted slot.
__global__ __launch_bounds__(256) void emsg_kernel(
    const int*   __restrict__ ssorted, const int* __restrict__ wpos,
    const int*   __restrict__ esorted,
    const float* __restrict__ hs,    // NE x 64, rows by edge id
    const float* __restrict__ T,     // NN x 2048
    const float* __restrict__ bv,    // NN x 32
    float*       __restrict__ msg)   // NE x 32, dst-sorted rows
{
    __shared__ float hl[8 * EHD];
    const int tid = threadIdx.x;
    const int p0  = blockIdx.x * 8;

    if (tid < 128) {   // 8 rows x 16 lanes: each group reads 256B contiguous
        const int q   = tid >> 4;
        const int eid = esorted[p0 + q];
        reinterpret_cast<float4*>(hl)[tid] =
            reinterpret_cast<const float4*>(hs + (size_t)eid * EHD)[tid & 15];
    }
    __syncthreads();

    const int sl = tid >> 5, o = tid & 31;
    const int p  = p0 + sl;
    const int s  = ssorted[p];
    const int wp = wpos[p];

    float hreg[EHD];
    #pragma unroll
    for (int q = 0; q < 16; ++q) {   // broadcast ds_read_b128
        const float4 v = reinterpret_cast<const float4*>(hl + sl * EHD)[q];
        hreg[q * 4] = v.x; hreg[q * 4 + 1] = v.y;
        hreg[q * 4 + 2] = v.z; hreg[q * 4 + 3] = v.w;
    }

    const float* tr = T + (size_t)s * 2048 + o;
    float a0 = bv[s * HD + o], a1 = 0.f;
    #pragma unroll
    for (int kh = 0; kh < EHD; kh += 2) {
        a0 = fmaf(hreg[kh],     tr[kh * 32],       a0);   // 128B coalesced/group
        a1 = fmaf(hreg[kh + 1], tr[(kh + 1) * 32], a1);
    }
    msg[(size_t)wp * HD + o] = a0 + a1;
}

// ---------------------------------------------------------------- NNConv contraction (fallback path)
__global__ __launch_bounds__(64) void nnconv_kernel(
    const float* __restrict__ xin, const int* __restrict__ src,
    const int* __restrict__ sortpos, const float* __restrict__ hT,
    const float* __restrict__ W2, const float* __restrict__ b2,
    float* __restrict__ msg)
{
    const int e  = blockIdx.x * 64 + threadIdx.x;
    const int oh = blockIdx.y * 16;
    const int s  = src[e];
    const int sp = sortpos[e];
    float xs[HD];
    {
        const float* xr = xin + s * HD;
        #pragma unroll
        for (int i = 0; i < HD; i += 4) {
            const float4 v = *reinterpret_cast<const float4*>(xr + i);
            xs[i] = v.x; xs[i + 1] = v.y; xs[i + 2] = v.z; xs[i + 3] = v.w;
        }
    }
    float acc[16];
    #pragma unroll
    for (int o = 0; o < 16; ++o) acc[o] = 0.f;
    #pragma unroll 1
    for (int kh = 0; kh < EHD; ++kh) {
        const float hk = hT[kh * NE + e];
        const float* w2k = W2 + kh * (HD * HD) + oh;
        #pragma unroll
        for (int i = 0; i < HD; ++i) {
            const float p = hk * xs[i];
            #pragma unroll
            for (int o = 0; o < 16; ++o)
                acc[o] = fmaf(p, w2k[i * HD + o], acc[o]);
        }
    }
    #pragma unroll 1
    for (int i = 0; i < HD; ++i) {
        const float xi = xs[i];
        const float* b2r = b2 + i * HD + oh;
        #pragma unroll
        for (int o = 0; o < 16; ++o)
            acc[o] = fmaf(xi, b2r[o], acc[o]);
    }
    float* mr = msg + sp * HD + oh;
    #pragma unroll
    for (int q = 0; q < 4; ++q) {
        float4 v;
        v.x = acc[q * 4 + 0]; v.y = acc[q * 4 + 1];
        v.z = acc[q * 4 + 2]; v.w = acc[q * 4 + 3];
        *reinterpret_cast<float4*>(mr + q * 4) = v;
    }
}

// ---------------------------------------------------------------- fused CSR-reduce + root GEMV + BN + relu
__global__ __launch_bounds__(256) void node_update_kernel(
    const int*   __restrict__ rowptr, const float* __restrict__ msg,
    const float* __restrict__ xin,
    const float* __restrict__ root, const float* __restrict__ bias,
    const float* __restrict__ bg, const float* __restrict__ bb,
    const float* __restrict__ brm, const float* __restrict__ brv,
    float* __restrict__ xout)
{
    const int gid = blockIdx.x * 256 + threadIdx.x;
    const int n = gid >> 5, o = gid & 31;
    float a = 0.f;
    const int j0 = rowptr[n], j1 = rowptr[n + 1];
    for (int j = j0; j < j1; ++j)
        a += msg[j * HD + o];
    const float* xr = xin + n * HD;
    #pragma unroll
    for (int i = 0; i < HD; ++i)
        a = fmaf(xr[i], root[i * HD + o], a);
    a += bias[o];
    a = (a - brm[o]) * rsqrtf(brv[o] + EPSF) * bg[o] + bb[o];
    xout[gid] = fmaxf(a, 0.f);
}

// ---------------------------------------------------------------- segment max pool
__global__ __launch_bounds__(256) void pool_kernel(
    const float* __restrict__ x, const int* __restrict__ batch,
    float* __restrict__ g)
{
    const int gid = blockIdx.x * 256 + threadIdx.x;
    const int n = gid >> 5, o = gid & 31;
    const float v = x[gid];
    atomicMax(reinterpret_cast<int*>(g) + batch[n] * HD + o, __float_as_int(v));
}

// ---------------------------------------------------------------- MLP head
__global__ __launch_bounds__(64) void head_kernel(
    const float* __restrict__ g, const float* __restrict__ l1W,
    const float* __restrict__ l1b, const float* __restrict__ l2W,
    const float* __restrict__ l2b, float* __restrict__ out)
{
    const int gr = threadIdx.x;
    const float* grow = g + gr * HD;
    float hv[HD];
    #pragma unroll
    for (int o = 0; o < HD; ++o) hv[o] = l1b[o];
    #pragma unroll
    for (int i = 0; i < HD; ++i) {
        const float gi = grow[i];
        #pragma unroll
        for (int o = 0; o < HD; ++o)
            hv[o] = fmaf(gi, l1W[i * HD + o], hv[o]);
    }
    float o0 = l2b[0], o1 = l2b[1];
    #pragma unroll
    for (int o = 0; o < HD; ++o) {
        const float r = fmaxf(hv[o], 0.f);
        o0 = fmaf(r, l2W[o * 2 + 0], o0);
        o1 = fmaf(r, l2W[o * 2 + 1], o1);
    }
    out[gr * 2 + 0] = o0;
    out[gr * 2 + 1] = o1;
}

// ---------------------------------------------------------------- launcher
extern "C" void kernel_launch(void* const* d_in, const int* in_sizes, int n_in,
                              void* d_out, int out_size, void* d_ws, size_t ws_size,
                              hipStream_t stream)
{
    const float* x     = (const float*)d_in[0];
    const int*   esrc  = (const int*)  d_in[1];
    const int*   edst  = (const int*)  d_in[2];
    const float* eattr = (const float*)d_in[3];
    const int*   batch = (const int*)  d_in[4];

    const float* c0W1   = (const float*)d_in[5];
    const float* c0b1   = (const float*)d_in[6];
    const float* c0W2   = (const float*)d_in[7];
    const float* c0b2   = (const float*)d_in[8];
    const float* c0root = (const float*)d_in[9];
    const float* c0bias = (const float*)d_in[10];
    const float* bn0g   = (const float*)d_in[11];
    const float* bn0b   = (const float*)d_in[12];
    const float* bn0rm  = (const float*)d_in[13];
    const float* bn0rv  = (const float*)d_in[14];

    const float* c1W1   = (const float*)d_in[15];
    const float* c1b1   = (const float*)d_in[16];
    const float* c1W2   = (const float*)d_in[17];
    const float* c1b2   = (const float*)d_in[18];
    const float* c1root = (const float*)d_in[19];
    const float* c1bias = (const float*)d_in[20];
    const float* bn1g   = (const float*)d_in[21];
    const float* bn1b   = (const float*)d_in[22];
    const float* bn1rm  = (const float*)d_in[23];
    const float* bn1rv  = (const float*)d_in[24];

    const float* l1W = (const float*)d_in[25];
    const float* l1b = (const float*)d_in[26];
    const float* l2W = (const float*)d_in[27];
    const float* l2b = (const float*)d_in[28];

    // ---- workspace layout (float units) ----
    float* ws   = (float*)d_ws;
    float* hbuf = ws;                        // NE*64 = 10,240,000 (hs or hT)
    float* msg  = ws + 10240000;             // NE*32 =  5,120,000
    float* x1   = ws + 15360000;             // 640,000
    float* x2   = ws + 16000000;             // 640,000
    float* gbuf = ws + 16640000;             // 2,048
    int* hist_d    = (int*)(ws + 16642048);  // 20,000
    int* hist_s    = (int*)(ws + 16662048);  // 20,000  (zero span: gbuf..hist_s = 42,048)
    int* rowptr_d  = (int*)(ws + 16682048);  // 20,001
    int* cursor_d  = (int*)(ws + 16702049);  // 20,000
    int* sortpos_d = (int*)(ws + 16722049);  // 160,000
    int* rowptr_s  = (int*)(ws + 16882049);  // 20,001
    int* cursor_s  = (int*)(ws + 16902050);  // 20,000
    int* ssorted   = (int*)(ws + 16922050);  // 160,000
    int* wpos      = (int*)(ws + 17082050);  // 160,000
    int* esorted   = (int*)(ws + 17242050);  // 160,000
    float* bv      = ws + 17402050;          // 640,000
    float* T       = ws + 18042050;          // 40,960,000
    const size_t NEED_NEW = (size_t)59002050 * 4;   // ~236 MB
    const bool use_fast = (ws_size >= NEED_NEW);

    // zero gbuf + hist_d + hist_s (contiguous 42,048)
    zero_kernel<<<165, 256, 0, stream>>>(gbuf, 42048);

    // dst-CSR (both paths)
    hist_kernel<<<NE / 256, 256, 0, stream>>>(edst, hist_d);
    scan_kernel<<<1, 1024, 0, stream>>>(hist_d, rowptr_d, cursor_d);
    scatter_dst_kernel<<<NE / 256, 256, 0, stream>>>(edst, cursor_d, sortpos_d);

    if (use_fast) {
        // src-CSR
        hist_kernel<<<NE / 256, 256, 0, stream>>>(esrc, hist_s);
        scan_kernel<<<1, 1024, 0, stream>>>(hist_s, rowptr_s, cursor_s);
        scatter_src_kernel<<<NE / 256, 256, 0, stream>>>(esrc, sortpos_d, cursor_s,
                                                         ssorted, wpos, esorted);
        const dim3 tgrid(NN / 8, 8);
        // layer 0
        bvec_kernel<<<NN * HD / 256, 256, 0, stream>>>(x, c0b2, bv);
        tmat_kernel<<<tgrid, 256, 0, stream>>>(x, c0W2, T);
        edge_mlp_v5_kernel<<<NE / EPW, 64, 0, stream>>>(eattr, c0W1, c0b1, hbuf);
        emsg_kernel<<<NE / 8, 256, 0, stream>>>(ssorted, wpos, esorted, hbuf, T, bv, msg);
        node_update_kernel<<<NN * HD / 256, 256, 0, stream>>>(rowptr_d, msg, x, c0root, c0bias,
                                                              bn0g, bn0b, bn0rm, bn0rv, x1);
        // layer 1
        bvec_kernel<<<NN * HD / 256, 256, 0, stream>>>(x1, c1b2, bv);
        tmat_kernel<<<tgrid, 256, 0, stream>>>(x1, c1W2, T);
        edge_mlp_v5_kernel<<<NE / EPW, 64, 0, stream>>>(eattr, c1W1, c1b1, hbuf);
        emsg_kernel<<<NE / 8, 256, 0, stream>>>(ssorted, wpos, esorted, hbuf, T, bv, msg);
        node_update_kernel<<<NN * HD / 256, 256, 0, stream>>>(rowptr_d, msg, x1, c1root, c1bias,
                                                              bn1g, bn1b, bn1rm, bn1rv, x2);
    } else {
        // fallback: round-4 structure (fits in ~70 MB)
        const dim3 egrid64(NE / 64, 2);
        edge_mlp_kernel<<<NE / 128, 256, 0, stream>>>(eattr, c0W1, c0b1, hbuf);
        nnconv_kernel<<<egrid64, 64, 0, stream>>>(x, esrc, sortpos_d, hbuf, c0W2, c0b2, msg);
        node_update_kernel<<<NN * HD / 256, 256, 0, stream>>>(rowptr_d, msg, x, c0root, c0bias,
                                                              bn0g, bn0b, bn0rm, bn0rv, x1);
        edge_mlp_kernel<<<NE / 128, 256, 0, stream>>>(eattr, c1W1, c1b1, hbuf);
        nnconv_kernel<<<egrid64, 64, 0, stream>>>(x1, esrc, sortpos_d, hbuf, c1W2, c1b2, msg);
        node_update_kernel<<<NN * HD / 256, 256, 0, stream>>>(rowptr_d, msg, x1, c1root, c1bias,
                                                              bn1g, bn1b, bn1rm, bn1rv, x2);
    }

    // pool + head
    pool_kernel<<<NN * HD / 256, 256, 0, stream>>>(x2, batch, gbuf);
    head_kernel<<<1, 64, 0, stream>>>(gbuf, l1W, l1b, l2W, l2b, (float*)d_out);
}

// Round 8
// 643.848 us; speedup vs baseline: 1.4105x; 1.4105x over previous
//
#include <hip/hip_runtime.h>

#define NN   20000   // nodes
#define NE   160000  // edges
#define HD   32      // hidden / in dim
#define EFD  95      // edge feature dim
#define EHD  64      // edge hidden dim
#define NG   64      // graphs
#define EPSF 1e-5f

// ---------------------------------------------------------------- zero fill
__global__ __launch_bounds__(256) void zero_kernel(float* __restrict__ p, int n) {
    int i = blockIdx.x * 256 + threadIdx.x;
    if (i < n) p[i] = 0.f;
}

// ---------------------------------------------------------------- CSR build: histogram
__global__ __launch_bounds__(256) void hist_kernel(const int* __restrict__ idx,
                                                   int* __restrict__ hist) {
    const int e = blockIdx.x * 256 + threadIdx.x;   // grid exactly NE/256
    atomicAdd(&hist[idx[e]], 1);
}

// ---------------------------------------------------------------- CSR build: exclusive scan (single block)
__global__ __launch_bounds__(1024) void scan_kernel(const int* __restrict__ hist,
                                                    int* __restrict__ rowptr,
                                                    int* __restrict__ cursor) {
    __shared__ int part[1024];
    const int t = threadIdx.x;
    const int base = t * 20;
    int s = 0;
    #pragma unroll
    for (int k = 0; k < 20; ++k) {
        const int idx = base + k;
        if (idx < NN) s += hist[idx];
    }
    part[t] = s;
    __syncthreads();
    for (int off = 1; off < 1024; off <<= 1) {
        int v = 0;
        if (t >= off) v = part[t - off];
        __syncthreads();
        if (t >= off) part[t] += v;
        __syncthreads();
    }
    int run = part[t] - s;   // exclusive offset for this chunk
    #pragma unroll
    for (int k = 0; k < 20; ++k) {
        const int idx = base + k;
        if (idx < NN) {
            rowptr[idx] = run;
            cursor[idx] = run;
            run += hist[idx];
        }
    }
    if (t == 0) rowptr[NN] = NE;
}

// ---------------------------------------------------------------- dst scatter -> sortpos_d
__global__ __launch_bounds__(256) void scatter_dst_kernel(const int* __restrict__ dst,
                                                          int* __restrict__ cursor,
                                                          int* __restrict__ sortpos) {
    const int e = blockIdx.x * 256 + threadIdx.x;
    sortpos[e] = atomicAdd(&cursor[dst[e]], 1);
}

// ---------------------------------------------------------------- src scatter -> ssorted/wpos/esorted
__global__ __launch_bounds__(256) void scatter_src_kernel(const int* __restrict__ src,
                                                          const int* __restrict__ sortpos_d,
                                                          int* __restrict__ cursor,
                                                          int* __restrict__ ssorted,
                                                          int* __restrict__ wpos,
                                                          int* __restrict__ esorted) {
    const int e = blockIdx.x * 256 + threadIdx.x;
    const int s = src[e];
    const int pos = atomicAdd(&cursor[s], 1);
    ssorted[pos] = s;            // src node of sorted slot
    wpos[pos]    = sortpos_d[e]; // where slot's msg goes (dst-sorted)
    esorted[pos] = e;            // edge id of sorted slot (for h gather)
}

// ---------------------------------------------------------------- edge MLP (fallback path, hT output)
__global__ __launch_bounds__(256) void edge_mlp_kernel(
    const float* __restrict__ ea, const float* __restrict__ W1,
    const float* __restrict__ b1, float* __restrict__ hT)   // EHD x NE
{
    __shared__ float elds[128 * EFD];
    const int tid = threadIdx.x;
    const int e0  = blockIdx.x * 128;
    const float4* s4 = reinterpret_cast<const float4*>(ea + (size_t)e0 * EFD);
    float4* d4 = reinterpret_cast<float4*>(elds);
    #pragma unroll
    for (int i = 0; i < 12; ++i) {
        const int idx = tid + i * 256;
        if (idx < (128 * EFD / 4)) d4[idx] = s4[idx];
    }
    __syncthreads();
    const int el = tid & 127;
    const int hh = (tid >> 7) * 32;
    const int e  = e0 + el;
    float acc[32];
    #pragma unroll
    for (int k = 0; k < 32; ++k) acc[k] = b1[hh + k];
    const float* er = elds + el * EFD;
    #pragma unroll 5
    for (int j = 0; j < EFD; ++j) {
        const float ej = er[j];
        const float* w1r = W1 + j * EHD + hh;
        #pragma unroll
        for (int k = 0; k < 32; ++k)
            acc[k] = fmaf(ej, w1r[k], acc[k]);
    }
    #pragma unroll
    for (int k = 0; k < 32; ++k)
        hT[(hh + k) * NE + e] = fmaxf(acc[k], 0.f);
}

// ---------------------------------------------------------------- edge MLP v7: register-tile GEMM
// Block 256 = tile 64 edges x 64 cols, thread = 4x4. Both operands in LDS,
// all inner-loop reads are ds_read_b128 on the VECTOR path (v5/v2 stall was
// a scalar-path operand serialized per iteration). A rows padded to stride
// 100 (16B-aligned, edge-group banks {0,16,8,24} -> conflict-free broadcast);
// W1 zero row 95 makes the j-tail uniform. 50KB LDS -> 3 blocks/CU.
__global__ __launch_bounds__(256) void edge_mlp_v7_kernel(
    const float* __restrict__ ea,    // NE x 95
    const float* __restrict__ W1,    // 95 x 64
    const float* __restrict__ b1,    // 64
    float*       __restrict__ hs)    // NE x 64, rows by edge id
{
    __shared__ float alds[64 * 100];   // 25.6 KB: 64 edges, stride 100
    __shared__ float wlds[96 * 64];    // 24.6 KB: 95 rows + zero row
    const int tid = threadIdx.x;
    const int e0  = blockIdx.x * 64;   // grid exactly NE/64

    // stage A: coalesced float4 reads; magic-div scatter into padded rows
    {
        const float4* s4 = reinterpret_cast<const float4*>(ea + (size_t)e0 * EFD);
        #pragma unroll
        for (int it = 0; it < 6; ++it) {
            const int idx4 = tid + it * 256;
            if (idx4 < (64 * EFD / 4)) {                 // 1520
                const float4 v = s4[idx4];
                const unsigned f = (unsigned)idx4 * 4u;
                const float vv[4] = {v.x, v.y, v.z, v.w};
                #pragma unroll
                for (int t = 0; t < 4; ++t) {
                    const unsigned ft = f + t;
                    const unsigned et = (ft * 44151u) >> 22;   // exact /95 for ft<6080
                    const unsigned jt = ft - 95u * et;
                    alds[et * 100 + jt] = vv[t];
                }
            }
        }
    }
    // stage W1: coalesced float4, layout preserved (stride 64)
    {
        const float4* w4 = reinterpret_cast<const float4*>(W1);
        float4* d4 = reinterpret_cast<float4*>(wlds);
        #pragma unroll
        for (int it = 0; it < 6; ++it) {
            const int idx4 = tid + it * 256;
            if (idx4 < (EFD * EHD / 4)) d4[idx4] = w4[idx4];   // 1520
        }
    }
    // zero pads: A col 95 (garbage guard), W1 row 95 (tail multiplies by 0)
    if (tid < 64) {
        alds[tid * 100 + 95] = 0.f;
        wlds[95 * 64 + tid]  = 0.f;
    }
    __syncthreads();

    const int tx = tid & 15;          // col group: cols 4tx..4tx+3
    const int ty = tid >> 4;          // edge group: edges 4ty..4ty+3

    float acc[4][4];
    {
        const float4 bv4 = *reinterpret_cast<const float4*>(b1 + 4 * tx);
        const float bb[4] = {bv4.x, bv4.y, bv4.z, bv4.w};
        #pragma unroll
        for (int i = 0; i < 4; ++i)
            #pragma unroll
            for (int c = 0; c < 4; ++c)
                acc[i][c] = bb[c];
    }

    // 24 j-quads (rows 92..95 use the zero pad row)
    for (int jq = 0; jq < 24; ++jq) {
        float w[4][4];                 // W1[4jq+r][4tx+c], unpacked static
        #pragma unroll
        for (int r = 0; r < 4; ++r) {
            const float4 wv = *reinterpret_cast<const float4*>(
                &wlds[(4 * jq + r) * 64 + 4 * tx]);
            w[r][0] = wv.x; w[r][1] = wv.y; w[r][2] = wv.z; w[r][3] = wv.w;
        }
        #pragma unroll
        for (int i = 0; i < 4; ++i) {
            const float4 av = *reinterpret_cast<const float4*>(
                &alds[(4 * ty + i) * 100 + 4 * jq]);
            #pragma unroll
            for (int c = 0; c < 4; ++c) {
                float t0 = fmaf(av.x, w[0][c], acc[i][c]);
                t0 = fmaf(av.y, w[1][c], t0);
                t0 = fmaf(av.z, w[2][c], t0);
                acc[i][c] = fmaf(av.w, w[3][c], t0);
            }
        }
    }

    // store: relu, per edge one float4; 16 lanes x 16B = 256B coalesced
    #pragma unroll
    for (int i = 0; i < 4; ++i) {
        const int e = e0 + 4 * ty + i;
        float4 v;
        v.x = fmaxf(acc[i][0], 0.f);
        v.y = fmaxf(acc[i][1], 0.f);
        v.z = fmaxf(acc[i][2], 0.f);
        v.w = fmaxf(acc[i][3], 0.f);
        *reinterpret_cast<float4*>(hs + (size_t)e * EHD + 4 * tx) = v;
    }
}

// ---------------------------------------------------------------- T = x @ W2r : T[n, kh*32+o] = sum_i x[n,i]*W2[kh][i*32+o]
__global__ __launch_bounds__(256) void tmat_kernel(
    const float* __restrict__ xin,   // NN x 32
    const float* __restrict__ W2,    // 64 x 1024
    float*       __restrict__ T)     // NN x 2048
{
    const int nb = blockIdx.x * 8;
    const int c  = blockIdx.y * 256 + threadIdx.x;   // 0..2047
    const int kh = c >> 5, o = c & 31;

    float w[32];
    const float* wp = W2 + kh * 1024 + o;
    #pragma unroll
    for (int i = 0; i < 32; ++i) w[i] = wp[i * 32];  // 128B coalesced / group

    #pragma unroll
    for (int nj = 0; nj < 8; ++nj) {
        const float* xr = xin + (nb + nj) * HD;      // uniform -> s_load
        float a0 = 0.f, a1 = 0.f;
        #pragma unroll
        for (int i = 0; i < 32; i += 2) {
            a0 = fmaf(xr[i],     w[i],     a0);
            a1 = fmaf(xr[i + 1], w[i + 1], a1);
        }
        T[(size_t)(nb + nj) * 2048 + c] = a0 + a1;   // 1KB coalesced / node
    }
}

// ---------------------------------------------------------------- bvec[n,o] = sum_i x[n,i]*b2[i*32+o]
__global__ __launch_bounds__(256) void bvec_kernel(
    const float* __restrict__ xin, const float* __restrict__ b2,
    float* __restrict__ bv)
{
    const int gid = blockIdx.x * 256 + threadIdx.x;  // NN*32/256
    const int n = gid >> 5, o = gid & 31;
    const float* xr = xin + n * HD;
    float a = 0.f;
    #pragma unroll
    for (int i = 0; i < 32; ++i)
        a = fmaf(xr[i], b2[i * HD + o], a);
    bv[gid] = a;
}

// ---------------------------------------------------------------- per-edge contraction over kh, src-sorted
__global__ __launch_bounds__(256) void emsg_kernel(
    const int*   __restrict__ ssorted, const int* __restrict__ wpos,
    const int*   __restrict__ esorted,
    const float* __restrict__ hs,    // NE x 64, rows by edge id
    const float* __restrict__ T,     // NN x 2048
    const float* __restrict__ bv,    // NN x 32
    float*       __restrict__ msg)   // NE x 32, dst-sorted rows
{
    __shared__ float hl[8 * EHD];
    const int tid = threadIdx.x;
    const int p0  = blockIdx.x * 8;

    if (tid < 128) {   // 8 rows x 16 lanes: each group reads 256B contiguous
        const int q   = tid >> 4;
        const int eid = esorted[p0 + q];
        reinterpret_cast<float4*>(hl)[tid] =
            reinterpret_cast<const float4*>(hs + (size_t)eid * EHD)[tid & 15];
    }
    __syncthreads();

    const int sl = tid >> 5, o = tid & 31;
    const int p  = p0 + sl;
    const int s  = ssorted[p];
    const int wp = wpos[p];

    float hreg[EHD];
    #pragma unroll
    for (int q = 0; q < 16; ++q) {   // broadcast ds_read_b128
        const float4 v = reinterpret_cast<const float4*>(hl + sl * EHD)[q];
        hreg[q * 4] = v.x; hreg[q * 4 + 1] = v.y;
        hreg[q * 4 + 2] = v.z; hreg[q * 4 + 3] = v.w;
    }

    const float* tr = T + (size_t)s * 2048 + o;
    float a0 = bv[s * HD + o], a1 = 0.f;
    #pragma unroll
    for (int kh = 0; kh < EHD; kh += 2) {
        a0 = fmaf(hreg[kh],     tr[kh * 32],       a0);   // 128B coalesced/group
        a1 = fmaf(hreg[kh + 1], tr[(kh + 1) * 32], a1);
    }
    msg[(size_t)wp * HD + o] = a0 + a1;
}

// ---------------------------------------------------------------- NNConv contraction (fallback path)
__global__ __launch_bounds__(64) void nnconv_kernel(
    const float* __restrict__ xin, const int* __restrict__ src,
    const int* __restrict__ sortpos, const float* __restrict__ hT,
    const float* __restrict__ W2, const float* __restrict__ b2,
    float* __restrict__ msg)
{
    const int e  = blockIdx.x * 64 + threadIdx.x;
    const int oh = blockIdx.y * 16;
    const int s  = src[e];
    const int sp = sortpos[e];
    float xs[HD];
    {
        const float* xr = xin + s * HD;
        #pragma unroll
        for (int i = 0; i < HD; i += 4) {
            const float4 v = *reinterpret_cast<const float4*>(xr + i);
            xs[i] = v.x; xs[i + 1] = v.y; xs[i + 2] = v.z; xs[i + 3] = v.w;
        }
    }
    float acc[16];
    #pragma unroll
    for (int o = 0; o < 16; ++o) acc[o] = 0.f;
    #pragma unroll 1
    for (int kh = 0; kh < EHD; ++kh) {
        const float hk = hT[kh * NE + e];
        const float* w2k = W2 + kh * (HD * HD) + oh;
        #pragma unroll
        for (int i = 0; i < HD; ++i) {
            const float p = hk * xs[i];
            #pragma unroll
            for (int o = 0; o < 16; ++o)
                acc[o] = fmaf(p, w2k[i * HD + o], acc[o]);
        }
    }
    #pragma unroll 1
    for (int i = 0; i < HD; ++i) {
        const float xi = xs[i];
        const float* b2r = b2 + i * HD + oh;
        #pragma unroll
        for (int o = 0; o < 16; ++o)
            acc[o] = fmaf(xi, b2r[o], acc[o]);
    }
    float* mr = msg + sp * HD + oh;
    #pragma unroll
    for (int q = 0; q < 4; ++q) {
        float4 v;
        v.x = acc[q * 4 + 0]; v.y = acc[q * 4 + 1];
        v.z = acc[q * 4 + 2]; v.w = acc[q * 4 + 3];
        *reinterpret_cast<float4*>(mr + q * 4) = v;
    }
}

// ---------------------------------------------------------------- fused CSR-reduce + root GEMV + BN + relu
__global__ __launch_bounds__(256) void node_update_kernel(
    const int*   __restrict__ rowptr, const float* __restrict__ msg,
    const float* __restrict__ xin,
    const float* __restrict__ root, const float* __restrict__ bias,
    const float* __restrict__ bg, const float* __restrict__ bb,
    const float* __restrict__ brm, const float* __restrict__ brv,
    float* __restrict__ xout)
{
    const int gid = blockIdx.x * 256 + threadIdx.x;
    const int n = gid >> 5, o = gid & 31;
    float a = 0.f;
    const int j0 = rowptr[n], j1 = rowptr[n + 1];
    for (int j = j0; j < j1; ++j)
        a += msg[j * HD + o];
    const float* xr = xin + n * HD;
    #pragma unroll
    for (int i = 0; i < HD; ++i)
        a = fmaf(xr[i], root[i * HD + o], a);
    a += bias[o];
    a = (a - brm[o]) * rsqrtf(brv[o] + EPSF) * bg[o] + bb[o];
    xout[gid] = fmaxf(a, 0.f);
}

// ---------------------------------------------------------------- layer-1 node update fused with graph max-pool
// Same as node_update but sinks relu(BN(...)) straight into gbuf via
// atomicMax (values >= 0, gbuf zero-init) -- drops the x2 write + pool pass.
__global__ __launch_bounds__(256) void node_update_pool_kernel(
    const int*   __restrict__ rowptr, const float* __restrict__ msg,
    const float* __restrict__ xin, const int* __restrict__ batch,
    const float* __restrict__ root, const float* __restrict__ bias,
    const float* __restrict__ bg, const float* __restrict__ bb,
    const float* __restrict__ brm, const float* __restrict__ brv,
    float* __restrict__ g)
{
    const int gid = blockIdx.x * 256 + threadIdx.x;
    const int n = gid >> 5, o = gid & 31;
    float a = 0.f;
    const int j0 = rowptr[n], j1 = rowptr[n + 1];
    for (int j = j0; j < j1; ++j)
        a += msg[j * HD + o];
    const float* xr = xin + n * HD;
    #pragma unroll
    for (int i = 0; i < HD; ++i)
        a = fmaf(xr[i], root[i * HD + o], a);
    a += bias[o];
    a = (a - brm[o]) * rsqrtf(brv[o] + EPSF) * bg[o] + bb[o];
    a = fmaxf(a, 0.f);
    atomicMax(reinterpret_cast<int*>(g) + batch[n] * HD + o, __float_as_int(a));
}

// ---------------------------------------------------------------- segment max pool (fallback path)
__global__ __launch_bounds__(256) void pool_kernel(
    const float* __restrict__ x, const int* __restrict__ batch,
    float* __restrict__ g)
{
    const int gid = blockIdx.x * 256 + threadIdx.x;
    const int n = gid >> 5, o = gid & 31;
    const float v = x[gid];
    atomicMax(reinterpret_cast<int*>(g) + batch[n] * HD + o, __float_as_int(v));
}

// ---------------------------------------------------------------- MLP head
__global__ __launch_bounds__(64) void head_kernel(
    const float* __restrict__ g, const float* __restrict__ l1W,
    const float* __restrict__ l1b, const float* __restrict__ l2W,
    const float* __restrict__ l2b, float* __restrict__ out)
{
    const int gr = threadIdx.x;
    const float* grow = g + gr * HD;
    float hv[HD];
    #pragma unroll
    for (int o = 0; o < HD; ++o) hv[o] = l1b[o];
    #pragma unroll
    for (int i = 0; i < HD; ++i) {
        const float gi = grow[i];
        #pragma unroll
        for (int o = 0; o < HD; ++o)
            hv[o] = fmaf(gi, l1W[i * HD + o], hv[o]);
    }
    float o0 = l2b[0], o1 = l2b[1];
    #pragma unroll
    for (int o = 0; o < HD; ++o) {
        const float r = fmaxf(hv[o], 0.f);
        o0 = fmaf(r, l2W[o * 2 + 0], o0);
        o1 = fmaf(r, l2W[o * 2 + 1], o1);
    }
    out[gr * 2 + 0] = o0;
    out[gr * 2 + 1] = o1;
}

// ---------------------------------------------------------------- launcher
extern "C" void kernel_launch(void* const* d_in, const int* in_sizes, int n_in,
                              void* d_out, int out_size, void* d_ws, size_t ws_size,
                              hipStream_t stream)
{
    const float* x     = (const float*)d_in[0];
    const int*   esrc  = (const int*)  d_in[1];
    const int*   edst  = (const int*)  d_in[2];
    const float* eattr = (const float*)d_in[3];
    const int*   batch = (const int*)  d_in[4];

    const float* c0W1   = (const float*)d_in[5];
    const float* c0b1   = (const float*)d_in[6];
    const float* c0W2   = (const float*)d_in[7];
    const float* c0b2   = (const float*)d_in[8];
    const float* c0root = (const float*)d_in[9];
    const float* c0bias = (const float*)d_in[10];
    const float* bn0g   = (const float*)d_in[11];
    const float* bn0b   = (const float*)d_in[12];
    const float* bn0rm  = (const float*)d_in[13];
    const float* bn0rv  = (const float*)d_in[14];

    const float* c1W1   = (const float*)d_in[15];
    const float* c1b1   = (const float*)d_in[16];
    const float* c1W2   = (const float*)d_in[17];
    const float* c1b2   = (const float*)d_in[18];
    const float* c1root = (const float*)d_in[19];
    const float* c1bias = (const float*)d_in[20];
    const float* bn1g   = (const float*)d_in[21];
    const float* bn1b   = (const float*)d_in[22];
    const float* bn1rm  = (const float*)d_in[23];
    const float* bn1rv  = (const float*)d_in[24];

    const float* l1W = (const float*)d_in[25];
    const float* l1b = (const float*)d_in[26];
    const float* l2W = (const float*)d_in[27];
    const float* l2b = (const float*)d_in[28];

    // ---- workspace layout (float units) ----
    float* ws   = (float*)d_ws;
    float* hbuf = ws;                        // NE*64 = 10,240,000 (hs or hT)
    float* msg  = ws + 10240000;             // NE*32 =  5,120,000
    float* x1   = ws + 15360000;             // 640,000
    float* x2   = ws + 16000000;             // 640,000 (fallback only)
    float* gbuf = ws + 16640000;             // 2,048
    int* hist_d    = (int*)(ws + 16642048);  // 20,000
    int* hist_s    = (int*)(ws + 16662048);  // 20,000  (zero span: gbuf..hist_s = 42,048)
    int* rowptr_d  = (int*)(ws + 16682048);  // 20,001
    int* cursor_d  = (int*)(ws + 16702049);  // 20,000
    int* sortpos_d = (int*)(ws + 16722049);  // 160,000
    int* rowptr_s  = (int*)(ws + 16882049);  // 20,001
    int* cursor_s  = (int*)(ws + 16902050);  // 20,000
    int* ssorted   = (int*)(ws + 16922050);  // 160,000
    int* wpos      = (int*)(ws + 17082050);  // 160,000
    int* esorted   = (int*)(ws + 17242050);  // 160,000
    float* bv      = ws + 17402050;          // 640,000
    float* T       = ws + 18042050;          // 40,960,000
    const size_t NEED_NEW = (size_t)59002050 * 4;   // ~236 MB
    const bool use_fast = (ws_size >= NEED_NEW);

    // zero gbuf + hist_d + hist_s (contiguous 42,048)
    zero_kernel<<<165, 256, 0, stream>>>(gbuf, 42048);

    // dst-CSR (both paths)
    hist_kernel<<<NE / 256, 256, 0, stream>>>(edst, hist_d);
    scan_kernel<<<1, 1024, 0, stream>>>(hist_d, rowptr_d, cursor_d);
    scatter_dst_kernel<<<NE / 256, 256, 0, stream>>>(edst, cursor_d, sortpos_d);

    if (use_fast) {
        // src-CSR
        hist_kernel<<<NE / 256, 256, 0, stream>>>(esrc, hist_s);
        scan_kernel<<<1, 1024, 0, stream>>>(hist_s, rowptr_s, cursor_s);
        scatter_src_kernel<<<NE / 256, 256, 0, stream>>>(esrc, sortpos_d, cursor_s,
                                                         ssorted, wpos, esorted);
        const dim3 tgrid(NN / 8, 8);
        // layer 0
        bvec_kernel<<<NN * HD / 256, 256, 0, stream>>>(x, c0b2, bv);
        tmat_kernel<<<tgrid, 256, 0, stream>>>(x, c0W2, T);
        edge_mlp_v7_kernel<<<NE / 64, 256, 0, stream>>>(eattr, c0W1, c0b1, hbuf);
        emsg_kernel<<<NE / 8, 256, 0, stream>>>(ssorted, wpos, esorted, hbuf, T, bv, msg);
        node_update_kernel<<<NN * HD / 256, 256, 0, stream>>>(rowptr_d, msg, x, c0root, c0bias,
                                                              bn0g, bn0b, bn0rm, bn0rv, x1);
        // layer 1
        bvec_kernel<<<NN * HD / 256, 256, 0, stream>>>(x1, c1b2, bv);
        tmat_kernel<<<tgrid, 256, 0, stream>>>(x1, c1W2, T);
        edge_mlp_v7_kernel<<<NE / 64, 256, 0, stream>>>(eattr, c1W1, c1b1, hbuf);
        emsg_kernel<<<NE / 8, 256, 0, stream>>>(ssorted, wpos, esorted, hbuf, T, bv, msg);
        node_update_pool_kernel<<<NN * HD / 256, 256, 0, stream>>>(rowptr_d, msg, x1, batch,
                                                                   c1root, c1bias,
                                                                   bn1g, bn1b, bn1rm, bn1rv, gbuf);
    } else {
        // fallback: round-4 structure (fits in ~70 MB)
        const dim3 egrid64(NE / 64, 2);
        edge_mlp_kernel<<<NE / 128, 256, 0, stream>>>(eattr, c0W1, c0b1, hbuf);
        nnconv_kernel<<<egrid64, 64, 0, stream>>>(x, esrc, sortpos_d, hbuf, c0W2, c0b2, msg);
        node_update_kernel<<<NN * HD / 256, 256, 0, stream>>>(rowptr_d, msg, x, c0root, c0bias,
                                                              bn0g, bn0b, bn0rm, bn0rv, x1);
        edge_mlp_kernel<<<NE / 128, 256, 0, stream>>>(eattr, c1W1, c1b1, hbuf);
        nnconv_kernel<<<egrid64, 64, 0, stream>>>(x1, esrc, sortpos_d, hbuf, c1W2, c1b2, msg);
        node_update_kernel<<<NN * HD / 256, 256, 0, stream>>>(rowptr_d, msg, x1, c1root, c1bias,
                                                              bn1g, bn1b, bn1rm, bn1rv, x2);
        pool_kernel<<<NN * HD / 256, 256, 0, stream>>>(x2, batch, gbuf);
    }

    // head
    head_kernel<<<1, 64, 0, stream>>>(gbuf, l1W, l1b, l2W, l2b, (float*)d_out);
}

// Round 9
// 606.989 us; speedup vs baseline: 1.4961x; 1.0607x over previous
//
#include <hip/hip_runtime.h>

#define NN   20000   // nodes
#define NE   160000  // edges
#define HD   32      // hidden / in dim
#define EFD  95      // edge feature dim
#define EHD  64      // edge hidden dim
#define NG   64      // graphs
#define EPSF 1e-5f
#define NPB  4       // src nodes per tmsg block

// ---------------------------------------------------------------- zero fill
__global__ __launch_bounds__(256) void zero_kernel(float* __restrict__ p, int n) {
    int i = blockIdx.x * 256 + threadIdx.x;
    if (i < n) p[i] = 0.f;
}

// ---------------------------------------------------------------- CSR build: histogram
__global__ __launch_bounds__(256) void hist_kernel(const int* __restrict__ idx,
                                                   int* __restrict__ hist) {
    const int e = blockIdx.x * 256 + threadIdx.x;   // grid exactly NE/256
    atomicAdd(&hist[idx[e]], 1);
}

// ---------------------------------------------------------------- CSR build: exclusive scan (single block)
__global__ __launch_bounds__(1024) void scan_kernel(const int* __restrict__ hist,
                                                    int* __restrict__ rowptr,
                                                    int* __restrict__ cursor) {
    __shared__ int part[1024];
    const int t = threadIdx.x;
    const int base = t * 20;
    int s = 0;
    #pragma unroll
    for (int k = 0; k < 20; ++k) {
        const int idx = base + k;
        if (idx < NN) s += hist[idx];
    }
    part[t] = s;
    __syncthreads();
    for (int off = 1; off < 1024; off <<= 1) {
        int v = 0;
        if (t >= off) v = part[t - off];
        __syncthreads();
        if (t >= off) part[t] += v;
        __syncthreads();
    }
    int run = part[t] - s;   // exclusive offset for this chunk
    #pragma unroll
    for (int k = 0; k < 20; ++k) {
        const int idx = base + k;
        if (idx < NN) {
            rowptr[idx] = run;
            cursor[idx] = run;
            run += hist[idx];
        }
    }
    if (t == 0) rowptr[NN] = NE;
}

// ---------------------------------------------------------------- dst scatter -> sortpos_d
__global__ __launch_bounds__(256) void scatter_dst_kernel(const int* __restrict__ dst,
                                                          int* __restrict__ cursor,
                                                          int* __restrict__ sortpos) {
    const int e = blockIdx.x * 256 + threadIdx.x;
    sortpos[e] = atomicAdd(&cursor[dst[e]], 1);
}

// ---------------------------------------------------------------- src scatter -> ssorted/wpos/esorted
__global__ __launch_bounds__(256) void scatter_src_kernel(const int* __restrict__ src,
                                                          const int* __restrict__ sortpos_d,
                                                          int* __restrict__ cursor,
                                                          int* __restrict__ ssorted,
                                                          int* __restrict__ wpos,
                                                          int* __restrict__ esorted) {
    const int e = blockIdx.x * 256 + threadIdx.x;
    const int s = src[e];
    const int pos = atomicAdd(&cursor[s], 1);
    ssorted[pos] = s;            // src node of sorted slot
    wpos[pos]    = sortpos_d[e]; // where slot's msg goes (dst-sorted)
    esorted[pos] = e;            // edge id of sorted slot (for h gather)
}

// ---------------------------------------------------------------- edge MLP (fallback path, hT output)
__global__ __launch_bounds__(256) void edge_mlp_kernel(
    const float* __restrict__ ea, const float* __restrict__ W1,
    const float* __restrict__ b1, float* __restrict__ hT)   // EHD x NE
{
    __shared__ float elds[128 * EFD];
    const int tid = threadIdx.x;
    const int e0  = blockIdx.x * 128;
    const float4* s4 = reinterpret_cast<const float4*>(ea + (size_t)e0 * EFD);
    float4* d4 = reinterpret_cast<float4*>(elds);
    #pragma unroll
    for (int i = 0; i < 12; ++i) {
        const int idx = tid + i * 256;
        if (idx < (128 * EFD / 4)) d4[idx] = s4[idx];
    }
    __syncthreads();
    const int el = tid & 127;
    const int hh = (tid >> 7) * 32;
    const int e  = e0 + el;
    float acc[32];
    #pragma unroll
    for (int k = 0; k < 32; ++k) acc[k] = b1[hh + k];
    const float* er = elds + el * EFD;
    #pragma unroll 5
    for (int j = 0; j < EFD; ++j) {
        const float ej = er[j];
        const float* w1r = W1 + j * EHD + hh;
        #pragma unroll
        for (int k = 0; k < 32; ++k)
            acc[k] = fmaf(ej, w1r[k], acc[k]);
    }
    #pragma unroll
    for (int k = 0; k < 32; ++k)
        hT[(hh + k) * NE + e] = fmaxf(acc[k], 0.f);
}

// ---------------------------------------------------------------- edge MLP v7: register-tile GEMM
// Block 256 = tile 64 edges x 64 cols, thread = 4x4. Both operands in LDS,
// all inner-loop reads ds_read_b128 on the vector path. 50KB LDS -> 3/CU.
__global__ __launch_bounds__(256) void edge_mlp_v7_kernel(
    const float* __restrict__ ea,    // NE x 95
    const float* __restrict__ W1,    // 95 x 64
    const float* __restrict__ b1,    // 64
    float*       __restrict__ hs)    // NE x 64, rows by edge id
{
    __shared__ float alds[64 * 100];   // 25.6 KB: 64 edges, stride 100
    __shared__ float wlds[96 * 64];    // 24.6 KB: 95 rows + zero row
    const int tid = threadIdx.x;
    const int e0  = blockIdx.x * 64;   // grid exactly NE/64

    // stage A: coalesced float4 reads; magic-div scatter into padded rows
    {
        const float4* s4 = reinterpret_cast<const float4*>(ea + (size_t)e0 * EFD);
        #pragma unroll
        for (int it = 0; it < 6; ++it) {
            const int idx4 = tid + it * 256;
            if (idx4 < (64 * EFD / 4)) {                 // 1520
                const float4 v = s4[idx4];
                const unsigned f = (unsigned)idx4 * 4u;
                const float vv[4] = {v.x, v.y, v.z, v.w};
                #pragma unroll
                for (int t = 0; t < 4; ++t) {
                    const unsigned ft = f + t;
                    const unsigned et = (ft * 44151u) >> 22;   // exact /95 for ft<6080
                    const unsigned jt = ft - 95u * et;
                    alds[et * 100 + jt] = vv[t];
                }
            }
        }
    }
    // stage W1: coalesced float4, layout preserved (stride 64)
    {
        const float4* w4 = reinterpret_cast<const float4*>(W1);
        float4* d4 = reinterpret_cast<float4*>(wlds);
        #pragma unroll
        for (int it = 0; it < 6; ++it) {
            const int idx4 = tid + it * 256;
            if (idx4 < (EFD * EHD / 4)) d4[idx4] = w4[idx4];   // 1520
        }
    }
    // zero pads: A col 95 (garbage guard), W1 row 95 (tail multiplies by 0)
    if (tid < 64) {
        alds[tid * 100 + 95] = 0.f;
        wlds[95 * 64 + tid]  = 0.f;
    }
    __syncthreads();

    const int tx = tid & 15;          // col group: cols 4tx..4tx+3
    const int ty = tid >> 4;          // edge group: edges 4ty..4ty+3

    float acc[4][4];
    {
        const float4 bv4 = *reinterpret_cast<const float4*>(b1 + 4 * tx);
        const float bb[4] = {bv4.x, bv4.y, bv4.z, bv4.w};
        #pragma unroll
        for (int i = 0; i < 4; ++i)
            #pragma unroll
            for (int c = 0; c < 4; ++c)
                acc[i][c] = bb[c];
    }

    for (int jq = 0; jq < 24; ++jq) {
        float w[4][4];
        #pragma unroll
        for (int r = 0; r < 4; ++r) {
            const float4 wv = *reinterpret_cast<const float4*>(
                &wlds[(4 * jq + r) * 64 + 4 * tx]);
            w[r][0] = wv.x; w[r][1] = wv.y; w[r][2] = wv.z; w[r][3] = wv.w;
        }
        #pragma unroll
        for (int i = 0; i < 4; ++i) {
            const float4 av = *reinterpret_cast<const float4*>(
                &alds[(4 * ty + i) * 100 + 4 * jq]);
            #pragma unroll
            for (int c = 0; c < 4; ++c) {
                float t0 = fmaf(av.x, w[0][c], acc[i][c]);
                t0 = fmaf(av.y, w[1][c], t0);
                t0 = fmaf(av.z, w[2][c], t0);
                acc[i][c] = fmaf(av.w, w[3][c], t0);
            }
        }
    }

    #pragma unroll
    for (int i = 0; i < 4; ++i) {
        const int e = e0 + 4 * ty + i;
        float4 v;
        v.x = fmaxf(acc[i][0], 0.f);
        v.y = fmaxf(acc[i][1], 0.f);
        v.z = fmaxf(acc[i][2], 0.f);
        v.w = fmaxf(acc[i][3], 0.f);
        *reinterpret_cast<float4*>(hs + (size_t)e * EHD + 4 * tx) = v;
    }
}

// ---------------------------------------------------------------- bvec[n,o] = sum_i x[n,i]*b2[i*32+o]
__global__ __launch_bounds__(256) void bvec_kernel(
    const float* __restrict__ xin, const float* __restrict__ b2,
    float* __restrict__ bv)
{
    const int gid = blockIdx.x * 256 + threadIdx.x;  // NN*32/256
    const int n = gid >> 5, o = gid & 31;
    const float* xr = xin + n * HD;
    float a = 0.f;
    #pragma unroll
    for (int i = 0; i < 32; ++i)
        a = fmaf(xr[i], b2[i * HD + o], a);
    bv[gid] = a;
}

// ---------------------------------------------------------------- fused T + edge contraction (tmat+emsg, no T in HBM)
// Block = NPB(4) consecutive src nodes. Phase 1: T rows (NPBx2048) into LDS
// (tmat's exact pattern: W2 col coalesced into VGPRs, x via uniform s_load).
// Phase 2: the nodes' src-sorted edge slots, 8 at a time (emsg inner loop),
// T read from LDS (lane-o consecutive: conflict-free; 2 rows/wave = free),
// msg written at dst-sorted slot. Kills the 164MB T write + 1.3GB L3 reread.
__global__ __launch_bounds__(256) void tmsg_kernel(
    const float* __restrict__ xin,     // NN x 32
    const float* __restrict__ W2,      // 64 x 1024
    const int*   __restrict__ rowptr_s,// NN+1
    const int*   __restrict__ ssorted, // NE
    const int*   __restrict__ wpos,    // NE
    const int*   __restrict__ esorted, // NE
    const float* __restrict__ hs,      // NE x 64, rows by edge id
    const float* __restrict__ bv,      // NN x 32
    float*       __restrict__ msg)     // NE x 32, dst-sorted rows
{
    __shared__ float Tl[NPB * 2048];   // 32 KB
    __shared__ float hl[8 * EHD];      // 2 KB
    const int tid = threadIdx.x;
    const int n0  = blockIdx.x * NPB;  // grid exactly NN/NPB

    // ---- phase 1: T rows into LDS ----
    #pragma unroll 1
    for (int cg = 0; cg < 8; ++cg) {
        const int c  = cg * 256 + tid;     // 0..2047
        const int kh = c >> 5, o = c & 31;
        float w[32];
        const float* wp = W2 + kh * 1024 + o;
        #pragma unroll
        for (int i = 0; i < 32; ++i) w[i] = wp[i * 32];   // 128B coalesced/group
        #pragma unroll
        for (int n = 0; n < NPB; ++n) {
            const float* xr = xin + (size_t)(n0 + n) * HD;  // uniform -> s_load
            float a0 = 0.f, a1 = 0.f;
            #pragma unroll
            for (int i = 0; i < 32; i += 2) {
                a0 = fmaf(xr[i],     w[i],     a0);
                a1 = fmaf(xr[i + 1], w[i + 1], a1);
            }
            Tl[n * 2048 + c] = a0 + a1;    // lanes consecutive -> conflict-free
        }
    }
    __syncthreads();

    // ---- phase 2: edges of these NPB nodes ----
    const int p_begin = rowptr_s[n0];
    const int p_end   = rowptr_s[n0 + NPB];
    const int sl = tid >> 5, o = tid & 31;

    #pragma unroll 1
    for (int pb = p_begin; pb < p_end; pb += 8) {
        const int nrows = min(8, p_end - pb);
        if (tid < nrows * 16) {   // stage h rows: 16 lanes x 256B contiguous
            const int q   = tid >> 4;
            const int eid = esorted[pb + q];
            reinterpret_cast<float4*>(hl)[tid] =
                reinterpret_cast<const float4*>(hs + (size_t)eid * EHD)[tid & 15];
        }
        __syncthreads();

        if (sl < nrows) {
            const int p  = pb + sl;
            const int s  = ssorted[p];         // in [n0, n0+NPB)
            const int wp = wpos[p];
            const float* hr = hl + sl * EHD;   // broadcast reads
            const float* tr = Tl + (s - n0) * 2048 + o;
            float a0 = bv[s * HD + o], a1 = 0.f;
            #pragma unroll
            for (int kh = 0; kh < EHD; kh += 2) {
                a0 = fmaf(hr[kh],     tr[kh * 32],       a0);
                a1 = fmaf(hr[kh + 1], tr[(kh + 1) * 32], a1);
            }
            msg[(size_t)wp * HD + o] = a0 + a1;
        }
        __syncthreads();   // protect hl before next stage
    }
}

// ---------------------------------------------------------------- NNConv contraction (fallback path)
__global__ __launch_bounds__(64) void nnconv_kernel(
    const float* __restrict__ xin, const int* __restrict__ src,
    const int* __restrict__ sortpos, const float* __restrict__ hT,
    const float* __restrict__ W2, const float* __restrict__ b2,
    float* __restrict__ msg)
{
    const int e  = blockIdx.x * 64 + threadIdx.x;
    const int oh = blockIdx.y * 16;
    const int s  = src[e];
    const int sp = sortpos[e];
    float xs[HD];
    {
        const float* xr = xin + s * HD;
        #pragma unroll
        for (int i = 0; i < HD; i += 4) {
            const float4 v = *reinterpret_cast<const float4*>(xr + i);
            xs[i] = v.x; xs[i + 1] = v.y; xs[i + 2] = v.z; xs[i + 3] = v.w;
        }
    }
    float acc[16];
    #pragma unroll
    for (int o = 0; o < 16; ++o) acc[o] = 0.f;
    #pragma unroll 1
    for (int kh = 0; kh < EHD; ++kh) {
        const float hk = hT[kh * NE + e];
        const float* w2k = W2 + kh * (HD * HD) + oh;
        #pragma unroll
        for (int i = 0; i < HD; ++i) {
            const float p = hk * xs[i];
            #pragma unroll
            for (int o = 0; o < 16; ++o)
                acc[o] = fmaf(p, w2k[i * HD + o], acc[o]);
        }
    }
    #pragma unroll 1
    for (int i = 0; i < HD; ++i) {
        const float xi = xs[i];
        const float* b2r = b2 + i * HD + oh;
        #pragma unroll
        for (int o = 0; o < 16; ++o)
            acc[o] = fmaf(xi, b2r[o], acc[o]);
    }
    float* mr = msg + sp * HD + oh;
    #pragma unroll
    for (int q = 0; q < 4; ++q) {
        float4 v;
        v.x = acc[q * 4 + 0]; v.y = acc[q * 4 + 1];
        v.z = acc[q * 4 + 2]; v.w = acc[q * 4 + 3];
        *reinterpret_cast<float4*>(mr + q * 4) = v;
    }
}

// ---------------------------------------------------------------- fused CSR-reduce + root GEMV + BN + relu
__global__ __launch_bounds__(256) void node_update_kernel(
    const int*   __restrict__ rowptr, const float* __restrict__ msg,
    const float* __restrict__ xin,
    const float* __restrict__ root, const float* __restrict__ bias,
    const float* __restrict__ bg, const float* __restrict__ bb,
    const float* __restrict__ brm, const float* __restrict__ brv,
    float* __restrict__ xout)
{
    const int gid = blockIdx.x * 256 + threadIdx.x;
    const int n = gid >> 5, o = gid & 31;
    float a = 0.f;
    const int j0 = rowptr[n], j1 = rowptr[n + 1];
    for (int j = j0; j < j1; ++j)
        a += msg[j * HD + o];
    const float* xr = xin + n * HD;
    #pragma unroll
    for (int i = 0; i < HD; ++i)
        a = fmaf(xr[i], root[i * HD + o], a);
    a += bias[o];
    a = (a - brm[o]) * rsqrtf(brv[o] + EPSF) * bg[o] + bb[o];
    xout[gid] = fmaxf(a, 0.f);
}

// ---------------------------------------------------------------- layer-1 node update fused with graph max-pool
__global__ __launch_bounds__(256) void node_update_pool_kernel(
    const int*   __restrict__ rowptr, const float* __restrict__ msg,
    const float* __restrict__ xin, const int* __restrict__ batch,
    const float* __restrict__ root, const float* __restrict__ bias,
    const float* __restrict__ bg, const float* __restrict__ bb,
    const float* __restrict__ brm, const float* __restrict__ brv,
    float* __restrict__ g)
{
    const int gid = blockIdx.x * 256 + threadIdx.x;
    const int n = gid >> 5, o = gid & 31;
    float a = 0.f;
    const int j0 = rowptr[n], j1 = rowptr[n + 1];
    for (int j = j0; j < j1; ++j)
        a += msg[j * HD + o];
    const float* xr = xin + n * HD;
    #pragma unroll
    for (int i = 0; i < HD; ++i)
        a = fmaf(xr[i], root[i * HD + o], a);
    a += bias[o];
    a = (a - brm[o]) * rsqrtf(brv[o] + EPSF) * bg[o] + bb[o];
    a = fmaxf(a, 0.f);
    atomicMax(reinterpret_cast<int*>(g) + batch[n] * HD + o, __float_as_int(a));
}

// ---------------------------------------------------------------- segment max pool (fallback path)
__global__ __launch_bounds__(256) void pool_kernel(
    const float* __restrict__ x, const int* __restrict__ batch,
    float* __restrict__ g)
{
    const int gid = blockIdx.x * 256 + threadIdx.x;
    const int n = gid >> 5, o = gid & 31;
    const float v = x[gid];
    atomicMax(reinterpret_cast<int*>(g) + batch[n] * HD + o, __float_as_int(v));
}

// ---------------------------------------------------------------- MLP head
__global__ __launch_bounds__(64) void head_kernel(
    const float* __restrict__ g, const float* __restrict__ l1W,
    const float* __restrict__ l1b, const float* __restrict__ l2W,
    const float* __restrict__ l2b, float* __restrict__ out)
{
    const int gr = threadIdx.x;
    const float* grow = g + gr * HD;
    float hv[HD];
    #pragma unroll
    for (int o = 0; o < HD; ++o) hv[o] = l1b[o];
    #pragma unroll
    for (int i = 0; i < HD; ++i) {
        const float gi = grow[i];
        #pragma unroll
        for (int o = 0; o < HD; ++o)
            hv[o] = fmaf(gi, l1W[i * HD + o], hv[o]);
    }
    float o0 = l2b[0], o1 = l2b[1];
    #pragma unroll
    for (int o = 0; o < HD; ++o) {
        const float r = fmaxf(hv[o], 0.f);
        o0 = fmaf(r, l2W[o * 2 + 0], o0);
        o1 = fmaf(r, l2W[o * 2 + 1], o1);
    }
    out[gr * 2 + 0] = o0;
    out[gr * 2 + 1] = o1;
}

// ---------------------------------------------------------------- launcher
extern "C" void kernel_launch(void* const* d_in, const int* in_sizes, int n_in,
                              void* d_out, int out_size, void* d_ws, size_t ws_size,
                              hipStream_t stream)
{
    const float* x     = (const float*)d_in[0];
    const int*   esrc  = (const int*)  d_in[1];
    const int*   edst  = (const int*)  d_in[2];
    const float* eattr = (const float*)d_in[3];
    const int*   batch = (const int*)  d_in[4];

    const float* c0W1   = (const float*)d_in[5];
    const float* c0b1   = (const float*)d_in[6];
    const float* c0W2   = (const float*)d_in[7];
    const float* c0b2   = (const float*)d_in[8];
    const float* c0root = (const float*)d_in[9];
    const float* c0bias = (const float*)d_in[10];
    const float* bn0g   = (const float*)d_in[11];
    const float* bn0b   = (const float*)d_in[12];
    const float* bn0rm  = (const float*)d_in[13];
    const float* bn0rv  = (const float*)d_in[14];

    const float* c1W1   = (const float*)d_in[15];
    const float* c1b1   = (const float*)d_in[16];
    const float* c1W2   = (const float*)d_in[17];
    const float* c1b2   = (const float*)d_in[18];
    const float* c1root = (const float*)d_in[19];
    const float* c1bias = (const float*)d_in[20];
    const float* bn1g   = (const float*)d_in[21];
    const float* bn1b   = (const float*)d_in[22];
    const float* bn1rm  = (const float*)d_in[23];
    const float* bn1rv  = (const float*)d_in[24];

    const float* l1W = (const float*)d_in[25];
    const float* l1b = (const float*)d_in[26];
    const float* l2W = (const float*)d_in[27];
    const float* l2b = (const float*)d_in[28];

    // ---- workspace layout (float units) ----
    float* ws   = (float*)d_ws;
    float* hbuf = ws;                        // NE*64 = 10,240,000 (hs or hT)
    float* msg  = ws + 10240000;             // NE*32 =  5,120,000
    float* x1   = ws + 15360000;             // 640,000
    float* x2   = ws + 16000000;             // 640,000 (fallback only)
    float* gbuf = ws + 16640000;             // 2,048
    int* hist_d    = (int*)(ws + 16642048);  // 20,000
    int* hist_s    = (int*)(ws + 16662048);  // 20,000  (zero span: gbuf..hist_s = 42,048)
    int* rowptr_d  = (int*)(ws + 16682048);  // 20,001
    int* cursor_d  = (int*)(ws + 16702049);  // 20,000
    int* sortpos_d = (int*)(ws + 16722049);  // 160,000
    int* rowptr_s  = (int*)(ws + 16882049);  // 20,001
    int* cursor_s  = (int*)(ws + 16902050);  // 20,000
    int* ssorted   = (int*)(ws + 16922050);  // 160,000
    int* wpos      = (int*)(ws + 17082050);  // 160,000
    int* esorted   = (int*)(ws + 17242050);  // 160,000
    float* bv      = ws + 17402050;          // 640,000
    const size_t NEED_NEW = (size_t)18042050 * 4;   // ~72 MB (T no longer materialized)
    const bool use_fast = (ws_size >= NEED_NEW);

    // zero gbuf + hist_d + hist_s (contiguous 42,048)
    zero_kernel<<<165, 256, 0, stream>>>(gbuf, 42048);

    // dst-CSR (both paths)
    hist_kernel<<<NE / 256, 256, 0, stream>>>(edst, hist_d);
    scan_kernel<<<1, 1024, 0, stream>>>(hist_d, rowptr_d, cursor_d);
    scatter_dst_kernel<<<NE / 256, 256, 0, stream>>>(edst, cursor_d, sortpos_d);

    if (use_fast) {
        // src-CSR
        hist_kernel<<<NE / 256, 256, 0, stream>>>(esrc, hist_s);
        scan_kernel<<<1, 1024, 0, stream>>>(hist_s, rowptr_s, cursor_s);
        scatter_src_kernel<<<NE / 256, 256, 0, stream>>>(esrc, sortpos_d, cursor_s,
                                                         ssorted, wpos, esorted);
        // layer 0
        bvec_kernel<<<NN * HD / 256, 256, 0, stream>>>(x, c0b2, bv);
        edge_mlp_v7_kernel<<<NE / 64, 256, 0, stream>>>(eattr, c0W1, c0b1, hbuf);
        tmsg_kernel<<<NN / NPB, 256, 0, stream>>>(x, c0W2, rowptr_s, ssorted, wpos,
                                                  esorted, hbuf, bv, msg);
        node_update_kernel<<<NN * HD / 256, 256, 0, stream>>>(rowptr_d, msg, x, c0root, c0bias,
                                                              bn0g, bn0b, bn0rm, bn0rv, x1);
        // layer 1
        bvec_kernel<<<NN * HD / 256, 256, 0, stream>>>(x1, c1b2, bv);
        edge_mlp_v7_kernel<<<NE / 64, 256, 0, stream>>>(eattr, c1W1, c1b1, hbuf);
        tmsg_kernel<<<NN / NPB, 256, 0, stream>>>(x1, c1W2, rowptr_s, ssorted, wpos,
                                                  esorted, hbuf, bv, msg);
        node_update_pool_kernel<<<NN * HD / 256, 256, 0, stream>>>(rowptr_d, msg, x1, batch,
                                                                   c1root, c1bias,
                                                                   bn1g, bn1b, bn1rm, bn1rv, gbuf);
    } else {
        // fallback: round-4 structure (fits in ~70 MB)
        const dim3 egrid64(NE / 64, 2);
        edge_mlp_kernel<<<NE / 128, 256, 0, stream>>>(eattr, c0W1, c0b1, hbuf);
        nnconv_kernel<<<egrid64, 64, 0, stream>>>(x, esrc, sortpos_d, hbuf, c0W2, c0b2, msg);
        node_update_kernel<<<NN * HD / 256, 256, 0, stream>>>(rowptr_d, msg, x, c0root, c0bias,
                                                              bn0g, bn0b, bn0rm, bn0rv, x1);
        edge_mlp_kernel<<<NE / 128, 256, 0, stream>>>(eattr, c1W1, c1b1, hbuf);
        nnconv_kernel<<<egrid64, 64, 0, stream>>>(x1, esrc, sortpos_d, hbuf, c1W2, c1b2, msg);
        node_update_kernel<<<NN * HD / 256, 256, 0, stream>>>(rowptr_d, msg, x1, c1root, c1bias,
                                                              bn1g, bn1b, bn1rm, bn1rv, x2);
        pool_kernel<<<NN * HD / 256, 256, 0, stream>>>(x2, batch, gbuf);
    }

    // head
    head_kernel<<<1, 64, 0, stream>>>(gbuf, l1W, l1b, l2W, l2b, (float*)d_out);
}